// Round 1
// baseline (2107.995 us; speedup 1.0000x reference)
//
#include <hip/hip_runtime.h>
#include <cstdint>
#include <cstddef>

// Problem constants (match reference setup_inputs)
#define NPTS 16384   // N
#define NSAMP 1024   // SAMPLES
#define KNBR 32      // MAX_NEIGHBORS
#define NCH 128      // C

// ---------------------------------------------------------------------------
// ROUND-4 THEORY: fps_kernel (1808 of 1932 us) runs on 4 of 256 CUs; active-CU
// VALUBusy ~76% => issue-bound serial loop, 4240 cyc/iter. FPS is serial over
// samples but parallel over points: split each batch over FPB=16 blocks
// (64 blocks total, all co-resident), exchange one 56-bit key per block per
// iteration through relaxed agent-scope atomics in d_ws. Tag+parity protocol:
// a block publishes s only after consuming s-1, so a slot holds s or s-2 only;
// 10-bit iteration tag distinguishes. Payload is inside the atomic key =>
// relaxed ordering suffices (coords re-read from immutable xyz).
//
// Exactness contract (absmax 0): d = (dx*dx+dy*dy)+dz*dz with contract(off)
// (packed v_pk_add/v_pk_mul are IEEE per-lane; a-b == add(a,-b) exact),
// md = fminf(md, d), argmax tie-break smallest global index (in-thread
// tournament prefers lower index on ties; cross-lane/wave/block via key
// (f32bits(val)<<24)|(idx^0x3FFF)<<10|tag — min-dists >= 0 so f32 bits are
// u32-monotone; ~idx makes bigger key == smaller index on value ties).
// ---------------------------------------------------------------------------

// ---- multi-block FPS config ----
#define FPB 16                    // blocks per batch
#define MB_TPB 256                // threads per block (4 waves)
#define MB_CHUNK (NPTS / FPB)     // 1024 points per block
#define MB_PPT (MB_CHUNK / MB_TPB)  // 4 points per thread

typedef float f32x2 __attribute__((ext_vector_type(2)));

__global__ void init_slots(unsigned long long* __restrict__ slots, int n) {
  const int i = blockIdx.x * blockDim.x + threadIdx.x;
  if (i < n) slots[i] = 0ull;  // tag 0 matches no iteration (s >= 1)
}

__global__ __launch_bounds__(MB_TPB, 1)
void fps_mb_kernel(const float* __restrict__ xyz,
                   float* __restrict__ centroids,
                   unsigned long long* __restrict__ slots) {
#pragma clang fp contract(off)
  const int gb = blockIdx.x;
  const int b = gb >> 4;          // batch (FPB == 16)
  const int k = gb & (FPB - 1);   // block within batch
  const int t = threadIdx.x;
  const int lane = t & 63;
  const int wave = t >> 6;

  const float* __restrict__ px = xyz + (size_t)b * NPTS * 3;
  float* co = centroids + (size_t)b * NSAMP * 3;
  unsigned long long* sl = slots + (size_t)b * (2 * FPB);

  // this thread's 4 points (ascending global index: p0 < p1 < p2 < p3)
  const int p0 = k * MB_CHUNK + t;
  const int p1 = p0 + MB_TPB;
  const int p2 = p0 + 2 * MB_TPB;
  const int p3 = p0 + 3 * MB_TPB;

  // packed pairs: A = (p0,p1), B = (p2,p3) -> v_pk_* f32 math
  f32x2 XA, YA, ZA, MA, XB, YB, ZB, MB2;
  XA.x = px[p0 * 3 + 0]; YA.x = px[p0 * 3 + 1]; ZA.x = px[p0 * 3 + 2];
  XA.y = px[p1 * 3 + 0]; YA.y = px[p1 * 3 + 1]; ZA.y = px[p1 * 3 + 2];
  XB.x = px[p2 * 3 + 0]; YB.x = px[p2 * 3 + 1]; ZB.x = px[p2 * 3 + 2];
  XB.y = px[p3 * 3 + 0]; YB.y = px[p3 * 3 + 1]; ZB.y = px[p3 * 3 + 2];
  MA = {1e10f, 1e10f};
  MB2 = {1e10f, 1e10f};

  __shared__ unsigned long long s_wkey[2][MB_TPB / 64];  // parity dbuf
  __shared__ unsigned long long s_win[2];
  __shared__ int s_abort;
  if (t == 0) s_abort = 0;  // ordered before first use by loop barrier #1

  float lx = px[0], ly = px[1], lz = px[2];
  if (k == 0 && t == 0) { co[0] = lx; co[1] = ly; co[2] = lz; }

  for (int s = 1; s < NSAMP; ++s) {
    const int par = s & 1;
    const f32x2 cx = {lx, lx};
    const f32x2 cy = {ly, ly};
    const f32x2 cz = {lz, lz};

    // packed distances + min update (contract(off): no FMA, exact op order)
    f32x2 dx = XA - cx, dy = YA - cy, dz = ZA - cz;
    f32x2 dd = (dx * dx + dy * dy) + dz * dz;
    MA.x = fminf(MA.x, dd.x);
    MA.y = fminf(MA.y, dd.y);
    dx = XB - cx; dy = YB - cy; dz = ZB - cz;
    dd = (dx * dx + dy * dy) + dz * dz;
    MB2.x = fminf(MB2.x, dd.x);
    MB2.y = fminf(MB2.y, dd.y);

    // tournament argmax, smaller-index wins ties (strict > on right operand)
    float v01, v23, bv;
    unsigned int i01, i23, bi;
    if (MA.y > MA.x) { v01 = MA.y; i01 = (unsigned int)p1; }
    else             { v01 = MA.x; i01 = (unsigned int)p0; }
    if (MB2.y > MB2.x) { v23 = MB2.y; i23 = (unsigned int)p3; }
    else               { v23 = MB2.x; i23 = (unsigned int)p2; }
    if (v23 > v01) { bv = v23; bi = i23; }
    else           { bv = v01; bi = i01; }

    // 56-bit key: value(32) | ~idx(14) | tag(10)
    unsigned long long key =
        ((unsigned long long)__float_as_uint(bv) << 24) |
        ((unsigned long long)(bi ^ 0x3FFFu) << 10) |
        (unsigned long long)(s & 1023);

    // intra-wave butterfly max (6 steps)
#pragma unroll
    for (int off = 1; off < 64; off <<= 1) {
      const unsigned long long ok = __shfl_xor(key, off);
      if (ok > key) key = ok;
    }
    if (lane == 0) s_wkey[par][wave] = key;
    __syncthreads();  // barrier #1

    if (wave == 0) {
      // cross-wave reduce (4 partials, broadcast LDS reads)
      unsigned long long bk = s_wkey[par][0];
#pragma unroll
      for (int w = 1; w < MB_TPB / 64; ++w) {
        const unsigned long long k2 = s_wkey[par][w];
        if (k2 > bk) bk = k2;
      }
      // publish block partial (relaxed agent atomic: payload is the key)
      if (lane == 0)
        __hip_atomic_store(&sl[par * FPB + k], bk, __ATOMIC_RELAXED,
                           __HIP_MEMORY_SCOPE_AGENT);
      // lanes 0..15 spin on the 16 slots (one 128B line per poll)
      unsigned long long v = 0;
      if (lane < FPB) {
        const unsigned long long want = (unsigned long long)(s & 1023);
        int g = 0;
        do {
          v = __hip_atomic_load(&sl[par * FPB + lane], __ATOMIC_RELAXED,
                                __HIP_MEMORY_SCOPE_AGENT);
        } while ((v & 1023ull) != want &&
                 __hip_atomic_load(&s_abort, __ATOMIC_RELAXED,
                                   __HIP_MEMORY_SCOPE_WORKGROUP) == 0 &&
                 ++g < (1 << 18));
        if (g >= (1 << 18))  // failsafe: never hang the harness
          __hip_atomic_store(&s_abort, 1, __ATOMIC_RELAXED,
                             __HIP_MEMORY_SCOPE_WORKGROUP);
      }
      // 16-lane butterfly (xor<16 stays within the lane group)
#pragma unroll
      for (int off = 1; off < FPB; off <<= 1) {
        const unsigned long long ov = __shfl_xor(v, off);
        if (ov > v) v = ov;
      }
      if (lane == 0) s_win[par] = v;
    }
    __syncthreads();  // barrier #2

    const unsigned long long wk = s_win[par];
    const unsigned int widx = (((unsigned int)(wk >> 10)) & 0x3FFFu) ^ 0x3FFFu;
    // winner coords: uniform address -> broadcast load, px never written
    lx = px[widx * 3 + 0];
    ly = px[widx * 3 + 1];
    lz = px[widx * 3 + 2];
    if (k == 0 && t == 0) {
      co[s * 3 + 0] = lx;
      co[s * 3 + 1] = ly;
      co[s * 3 + 2] = lz;
    }
  }
}

// ---------------------------------------------------------------------------
// Fallback: round-3 single-block-per-batch FPS (used only if d_ws too small).
// ---------------------------------------------------------------------------
#define FPS_TPB 512
#define FPS_PPT (NPTS / FPS_TPB)

#define PT_FOREACH(X) \
  X(0) X(1) X(2) X(3) X(4) X(5) X(6) X(7) \
  X(8) X(9) X(10) X(11) X(12) X(13) X(14) X(15) \
  X(16) X(17) X(18) X(19) X(20) X(21) X(22) X(23) \
  X(24) X(25) X(26) X(27) X(28) X(29) X(30) X(31)

__global__ __launch_bounds__(FPS_TPB)
__attribute__((amdgpu_waves_per_eu(2, 2)))
void fps_kernel(
    const float* __restrict__ xyz, float* __restrict__ centroids) {
#pragma clang fp contract(off)
  const int b = blockIdx.x;
  const int t = threadIdx.x;
  const float* px = xyz + (size_t)b * NPTS * 3;

#define DECL_PT(i) float x##i, y##i, z##i, m##i;
  PT_FOREACH(DECL_PT)
#undef DECL_PT

#define LOAD_PT(i)                              \
  {                                             \
    const int p = (i) * FPS_TPB + t;            \
    x##i = px[p * 3 + 0];                       \
    y##i = px[p * 3 + 1];                       \
    z##i = px[p * 3 + 2];                       \
    m##i = 1e10f;                               \
  }
  PT_FOREACH(LOAD_PT)
#undef LOAD_PT

  __shared__ unsigned long long s_wkey[2][FPS_TPB / 64];

  float* co = centroids + (size_t)b * NSAMP * 3;
  float lx = px[0], ly = px[1], lz = px[2];
  if (t == 0) { co[0] = lx; co[1] = ly; co[2] = lz; }

  for (int s = 1; s < NSAMP; ++s) {
    float bv = -1.0f;
    int bj = 0;
#define UPD_PT(i)                                                   \
    {                                                               \
      const float dx = x##i - lx;                                   \
      const float dy = y##i - ly;                                   \
      const float dz = z##i - lz;                                   \
      const float d = (dx * dx + dy * dy) + dz * dz;                \
      const float mm = fminf(m##i, d);                              \
      m##i = mm;                                                    \
      if (mm > bv) { bv = mm; bj = (i); }                           \
    }
    PT_FOREACH(UPD_PT)
#undef UPD_PT

    const unsigned int bi = (unsigned int)(bj * FPS_TPB + t);
    unsigned long long key =
        ((unsigned long long)__float_as_uint(bv) << 32) | (unsigned int)(~bi);

#pragma unroll
    for (int off = 1; off < 64; off <<= 1) {
      const unsigned long long ok = __shfl_xor(key, off);
      if (ok > key) key = ok;
    }
    if ((t & 63) == 0) s_wkey[s & 1][t >> 6] = key;
    __syncthreads();

    unsigned long long best = s_wkey[s & 1][0];
#pragma unroll
    for (int w = 1; w < FPS_TPB / 64; ++w) {
      const unsigned long long k2 = s_wkey[s & 1][w];
      if (k2 > best) best = k2;
    }
    const unsigned int widx = ~(unsigned int)best;

    lx = px[widx * 3 + 0];
    ly = px[widx * 3 + 1];
    lz = px[widx * 3 + 2];
    if (t == 0) {
      co[s * 3 + 0] = lx;
      co[s * 3 + 1] = ly;
      co[s * 3 + 2] = lz;
    }
  }
}

// ---------------------------------------------------------------------------
// Kernel 2: ball query + gather (validated bit-exact in round 0; unchanged).
// ---------------------------------------------------------------------------
__global__ __launch_bounds__(256) void group_kernel(
    const float* __restrict__ xyz, const float* __restrict__ feat,
    const float* __restrict__ centroids,
    float* __restrict__ gxyz, float* __restrict__ gfeat) {
#pragma clang fp contract(off)
  const int wave = threadIdx.x >> 6;
  const int lane = threadIdx.x & 63;
  const int gw = blockIdx.x * 4 + wave;  // == b * NSAMP + s
  const int b = gw >> 10;

  const float* px = xyz + (size_t)b * NPTS * 3;
  const float* pc = centroids + (size_t)gw * 3;
  const float cx = pc[0], cy = pc[1], cz = pc[2];
  const float rr = 0.04f;  // float32(0.04), NOT 0.2f*0.2f

  __shared__ int sh_idx[4][KNBR];
  __shared__ float sh_gx[4][KNBR * 3];

  int cnt = 0;
  for (int n0 = 0; n0 < NPTS && cnt < KNBR; n0 += 64) {
    const int p = n0 + lane;
    const float xx = px[p * 3 + 0];
    const float yy = px[p * 3 + 1];
    const float zz = px[p * 3 + 2];
    const float dx = xx - cx;
    const float dy = yy - cy;
    const float dz = zz - cz;
    const float d = (dx * dx + dy * dy) + dz * dz;
    const bool in = d <= rr;
    const unsigned long long mask = __ballot(in);
    const int pos = cnt + (int)__popcll(mask & ((1ull << lane) - 1ull));
    if (in && pos < KNBR) {
      sh_idx[wave][pos] = p;
      sh_gx[wave][pos * 3 + 0] = dx;
      sh_gx[wave][pos * 3 + 1] = dy;
      sh_gx[wave][pos * 3 + 2] = dz;
    }
    cnt += (int)__popcll(mask);
  }
  if (cnt == 0 && lane == 0) {
    sh_idx[wave][0] = 0;
    sh_gx[wave][0] = px[0] - cx;
    sh_gx[wave][1] = px[1] - cy;
    sh_gx[wave][2] = px[2] - cz;
  }
  const int nf0 = (cnt < 1) ? 1 : cnt;
  const int nf = (nf0 < KNBR) ? nf0 : KNBR;
  __syncthreads();
  if (lane < KNBR && lane >= nf) {
    sh_idx[wave][lane] = sh_idx[wave][0];
    sh_gx[wave][lane * 3 + 0] = sh_gx[wave][0];
    sh_gx[wave][lane * 3 + 1] = sh_gx[wave][1];
    sh_gx[wave][lane * 3 + 2] = sh_gx[wave][2];
  }
  __syncthreads();

  float* ox = gxyz + (size_t)gw * KNBR * 3;
  const float* shf = sh_gx[wave];
  for (int j = lane; j < KNBR * 3; j += 64) ox[j] = shf[j];

  float* og = gfeat + (size_t)gw * KNBR * NCH;
  const float* pf = feat + (size_t)b * NPTS * NCH;
#pragma unroll 4
  for (int k = 0; k < KNBR; ++k) {
    const int row = sh_idx[wave][k];
    const float2 v = ((const float2*)(pf + (size_t)row * NCH))[lane];
    ((float2*)(og + (size_t)k * NCH))[lane] = v;
  }
}

extern "C" void kernel_launch(void* const* d_in, const int* in_sizes, int n_in,
                              void* d_out, int out_size, void* d_ws, size_t ws_size,
                              hipStream_t stream) {
  const float* xyz = (const float*)d_in[0];
  const float* feat = (const float*)d_in[1];
  float* out = (float*)d_out;
  const int B = in_sizes[0] / (NPTS * 3);

  float* centroids = out;                                   // [B,S,3]
  float* gxyz = centroids + (size_t)B * NSAMP * 3;          // [B,S,K,3]
  float* gfeat = gxyz + (size_t)B * NSAMP * KNBR * 3;       // [B,S,K,C]

  const size_t slots_bytes =
      (size_t)B * 2 * FPB * sizeof(unsigned long long);
  if (d_ws != nullptr && ws_size >= slots_bytes) {
    unsigned long long* slots = (unsigned long long*)d_ws;
    init_slots<<<1, 256, 0, stream>>>(slots, B * 2 * FPB);
    fps_mb_kernel<<<B * FPB, MB_TPB, 0, stream>>>(xyz, centroids, slots);
  } else {
    fps_kernel<<<B, FPS_TPB, 0, stream>>>(xyz, centroids);  // fallback
  }
  group_kernel<<<(B * NSAMP) / 4, 256, 0, stream>>>(xyz, feat, centroids, gxyz,
                                                    gfeat);
}

// Round 2
// 1909.087 us; speedup vs baseline: 1.1042x; 1.1042x over previous
//
#include <hip/hip_runtime.h>
#include <cstdint>
#include <cstddef>

// Problem constants (match reference setup_inputs)
#define NPTS 16384   // N
#define NSAMP 1024   // SAMPLES
#define KNBR 32      // MAX_NEIGHBORS
#define NCH 128      // C

// ---------------------------------------------------------------------------
// ROUND-5 THEORY: round-4 multi-block FPS (1997us) validated the cross-block
// tag+parity protocol but stacked ~1500-2000 cyc/iter of LOCAL orchestration
// (2 barriers, 2 LDS hops, wave0-only reduce, fat poll body with LDS abort
// check) serially on the LLC round trip. Round 5: 1 wave per block -> publish
// gate is per-wave, so NO barriers and NO LDS in the loop; store issues right
// after the wave butterfly; poll body is load+and+cmp only; all 64 lanes poll
// (lane&15 -> one 128B line) so post-poll reduce is a 4-step butterfly.
//
// Protocol safety (proof carries from round 4, gate now per-wave): slot
// sl[par][w] is overwritten by its owner at s+2 only after the owner consumed
// s+1; every wave published s+1 only after consuming s; so when any slot of
// iteration s is overwritten, ALL waves have already consumed s. Tags 1..1023
// never alias zero-init or the s vs s+2 reuse. Relaxed agent atomics suffice:
// the 56-bit payload rides inside the atomic value itself.
//
// Exactness contract (absmax 0): d = (dx*dx+dy*dy)+dz*dz, contract(off), no
// FMA (packed v_pk_add/mul are IEEE per-lane); md = fminf(md,d); argmax
// tie-break smallest global index: in-pair strict > picks .x (smaller idx) on
// ties, pair-vs-running strict > keeps earlier pair (smaller idx), cross-lane
// via key (f32bits(v)<<24)|(idx^0x3FFF)<<10|tag — min-dists >= 0 so f32 bits
// are u32-monotone; ~idx makes larger key == smaller index on value ties.
// ---------------------------------------------------------------------------

#define FPB2 16                 // waves (blocks) per batch
#define W2_TPB 64               // 1 wave per block
// each lane owns 16 points as 8 packed pairs: p = k*1024 + slot*64 + lane

typedef float f32x2 __attribute__((ext_vector_type(2)));

__global__ void init_slots(unsigned long long* __restrict__ slots, int n) {
  const int i = blockIdx.x * blockDim.x + threadIdx.x;
  if (i < n) slots[i] = 0ull;  // tag 0 matches no iteration (s >= 1)
}

__global__ __launch_bounds__(W2_TPB)
void fps_mb2_kernel(const float* __restrict__ xyz,
                    float* __restrict__ centroids,
                    unsigned long long* __restrict__ slots) {
#pragma clang fp contract(off)
  const int b = blockIdx.x >> 4;          // batch (FPB2 == 16)
  const int k = blockIdx.x & (FPB2 - 1);  // wave within batch
  const int lane = threadIdx.x;           // 0..63

  const float* __restrict__ px = xyz + (size_t)b * NPTS * 3;
  float* co = centroids + (size_t)b * NSAMP * 3;
  unsigned long long* sl = slots + (size_t)b * (2 * FPB2);
  const unsigned int base_kl = (unsigned int)(k * 1024 + lane);

#define PAIR_FOREACH(X) X(0) X(1) X(2) X(3) X(4) X(5) X(6) X(7)

#define DECL_PR(j) f32x2 X##j, Y##j, Z##j, M##j;
  PAIR_FOREACH(DECL_PR)
#undef DECL_PR

#define LOAD_PR(j)                                              \
  {                                                             \
    const int pa = k * 1024 + (2 * (j)) * 64 + lane;            \
    const int pb = pa + 64;                                     \
    X##j.x = px[pa * 3 + 0];                                    \
    Y##j.x = px[pa * 3 + 1];                                    \
    Z##j.x = px[pa * 3 + 2];                                    \
    X##j.y = px[pb * 3 + 0];                                    \
    Y##j.y = px[pb * 3 + 1];                                    \
    Z##j.y = px[pb * 3 + 2];                                    \
    M##j = {1e10f, 1e10f};                                      \
  }
  PAIR_FOREACH(LOAD_PR)
#undef LOAD_PR

  float lx = px[0], ly = px[1], lz = px[2];
  if (k == 0 && lane == 0) { co[0] = lx; co[1] = ly; co[2] = lz; }
  bool dead = false;  // failsafe: bounded polling, never hang the harness

  for (int s = 1; s < NSAMP; ++s) {
    const int par = s & 1;
    const f32x2 cx = {lx, lx};
    const f32x2 cy = {ly, ly};
    const f32x2 cz = {lz, lz};

    // packed distances + min update (contract(off): exact op order, no FMA)
    float bv = -1.0f;
    int bs = 0;  // best slot index 0..15 (compile-time consts in cndmask)
#define UPD_PR(j)                                                       \
    {                                                                   \
      f32x2 dx = X##j - cx, dy = Y##j - cy, dz = Z##j - cz;             \
      f32x2 dd = (dx * dx + dy * dy) + dz * dz;                         \
      M##j.x = fminf(M##j.x, dd.x);                                     \
      M##j.y = fminf(M##j.y, dd.y);                                     \
      float vj; int sj;                                                 \
      if (M##j.y > M##j.x) { vj = M##j.y; sj = 2 * (j) + 1; }           \
      else                 { vj = M##j.x; sj = 2 * (j); }               \
      if (vj > bv) { bv = vj; bs = sj; }                                \
    }
    PAIR_FOREACH(UPD_PR)
#undef UPD_PR

    // global point index: k*1024 + slot*64 + lane  (14 bits)
    const unsigned int bi = base_kl + ((unsigned int)bs << 6);
    unsigned long long key =
        ((unsigned long long)__float_as_uint(bv) << 24) |
        ((unsigned long long)(bi ^ 0x3FFFu) << 10) |
        (unsigned long long)(s & 1023);

    // intra-wave butterfly max (6 steps) -> lane0 publishes immediately
#pragma unroll
    for (int off = 1; off < 64; off <<= 1) {
      const unsigned long long ok = __shfl_xor(key, off);
      if (ok > key) key = ok;
    }
    if (lane == 0)
      __hip_atomic_store(&sl[par * FPB2 + k], key, __ATOMIC_RELAXED,
                         __HIP_MEMORY_SCOPE_AGENT);

    // all 64 lanes poll (lane&15 -> 16 u64 = one 128B line per transaction)
    const unsigned int want = (unsigned int)(s & 1023);
    unsigned long long* myslot = &sl[par * FPB2 + (lane & 15)];
    unsigned long long v =
        __hip_atomic_load(myslot, __ATOMIC_RELAXED, __HIP_MEMORY_SCOPE_AGENT);
    if (!dead) {
      int g = 0;
      while (((unsigned int)v & 1023u) != want) {
        if (++g >= (1 << 17)) { dead = true; break; }  // cold path only
        v = __hip_atomic_load(myslot, __ATOMIC_RELAXED,
                              __HIP_MEMORY_SCOPE_AGENT);
      }
    }

    // 4-step butterfly: each 16-lane xor-group spans all 16 slots
#pragma unroll
    for (int off = 1; off < 16; off <<= 1) {
      const unsigned long long ov = __shfl_xor(v, off);
      if (ov > v) v = ov;
    }

    const unsigned int widx = (((unsigned int)(v >> 10)) & 0x3FFFu) ^ 0x3FFFu;
    // winner coords: uniform address -> broadcast load; px never written
    lx = px[widx * 3 + 0];
    ly = px[widx * 3 + 1];
    lz = px[widx * 3 + 2];
    if (k == 0 && lane == 0) {
      co[s * 3 + 0] = lx;
      co[s * 3 + 1] = ly;
      co[s * 3 + 2] = lz;
    }
  }
}

// ---------------------------------------------------------------------------
// Fallback: round-3 single-block-per-batch FPS (used only if d_ws too small).
// ---------------------------------------------------------------------------
#define FPS_TPB 512
#define FPS_PPT (NPTS / FPS_TPB)

#define PT_FOREACH(X) \
  X(0) X(1) X(2) X(3) X(4) X(5) X(6) X(7) \
  X(8) X(9) X(10) X(11) X(12) X(13) X(14) X(15) \
  X(16) X(17) X(18) X(19) X(20) X(21) X(22) X(23) \
  X(24) X(25) X(26) X(27) X(28) X(29) X(30) X(31)

__global__ __launch_bounds__(FPS_TPB)
__attribute__((amdgpu_waves_per_eu(2, 2)))
void fps_kernel(
    const float* __restrict__ xyz, float* __restrict__ centroids) {
#pragma clang fp contract(off)
  const int b = blockIdx.x;
  const int t = threadIdx.x;
  const float* px = xyz + (size_t)b * NPTS * 3;

#define DECL_PT(i) float x##i, y##i, z##i, m##i;
  PT_FOREACH(DECL_PT)
#undef DECL_PT

#define LOAD_PT(i)                              \
  {                                             \
    const int p = (i) * FPS_TPB + t;            \
    x##i = px[p * 3 + 0];                       \
    y##i = px[p * 3 + 1];                       \
    z##i = px[p * 3 + 2];                       \
    m##i = 1e10f;                               \
  }
  PT_FOREACH(LOAD_PT)
#undef LOAD_PT

  __shared__ unsigned long long s_wkey[2][FPS_TPB / 64];

  float* co = centroids + (size_t)b * NSAMP * 3;
  float lx = px[0], ly = px[1], lz = px[2];
  if (t == 0) { co[0] = lx; co[1] = ly; co[2] = lz; }

  for (int s = 1; s < NSAMP; ++s) {
    float bv = -1.0f;
    int bj = 0;
#define UPD_PT(i)                                                   \
    {                                                               \
      const float dx = x##i - lx;                                   \
      const float dy = y##i - ly;                                   \
      const float dz = z##i - lz;                                   \
      const float d = (dx * dx + dy * dy) + dz * dz;                \
      const float mm = fminf(m##i, d);                              \
      m##i = mm;                                                    \
      if (mm > bv) { bv = mm; bj = (i); }                           \
    }
    PT_FOREACH(UPD_PT)
#undef UPD_PT

    const unsigned int bi = (unsigned int)(bj * FPS_TPB + t);
    unsigned long long key =
        ((unsigned long long)__float_as_uint(bv) << 32) | (unsigned int)(~bi);

#pragma unroll
    for (int off = 1; off < 64; off <<= 1) {
      const unsigned long long ok = __shfl_xor(key, off);
      if (ok > key) key = ok;
    }
    if ((t & 63) == 0) s_wkey[s & 1][t >> 6] = key;
    __syncthreads();

    unsigned long long best = s_wkey[s & 1][0];
#pragma unroll
    for (int w = 1; w < FPS_TPB / 64; ++w) {
      const unsigned long long k2 = s_wkey[s & 1][w];
      if (k2 > best) best = k2;
    }
    const unsigned int widx = ~(unsigned int)best;

    lx = px[widx * 3 + 0];
    ly = px[widx * 3 + 1];
    lz = px[widx * 3 + 2];
    if (t == 0) {
      co[s * 3 + 0] = lx;
      co[s * 3 + 1] = ly;
      co[s * 3 + 2] = lz;
    }
  }
}

// ---------------------------------------------------------------------------
// Kernel 2: ball query + gather (validated bit-exact in round 0; unchanged).
// ---------------------------------------------------------------------------
__global__ __launch_bounds__(256) void group_kernel(
    const float* __restrict__ xyz, const float* __restrict__ feat,
    const float* __restrict__ centroids,
    float* __restrict__ gxyz, float* __restrict__ gfeat) {
#pragma clang fp contract(off)
  const int wave = threadIdx.x >> 6;
  const int lane = threadIdx.x & 63;
  const int gw = blockIdx.x * 4 + wave;  // == b * NSAMP + s
  const int b = gw >> 10;

  const float* px = xyz + (size_t)b * NPTS * 3;
  const float* pc = centroids + (size_t)gw * 3;
  const float cx = pc[0], cy = pc[1], cz = pc[2];
  const float rr = 0.04f;  // float32(0.04), NOT 0.2f*0.2f

  __shared__ int sh_idx[4][KNBR];
  __shared__ float sh_gx[4][KNBR * 3];

  int cnt = 0;
  for (int n0 = 0; n0 < NPTS && cnt < KNBR; n0 += 64) {
    const int p = n0 + lane;
    const float xx = px[p * 3 + 0];
    const float yy = px[p * 3 + 1];
    const float zz = px[p * 3 + 2];
    const float dx = xx - cx;
    const float dy = yy - cy;
    const float dz = zz - cz;
    const float d = (dx * dx + dy * dy) + dz * dz;
    const bool in = d <= rr;
    const unsigned long long mask = __ballot(in);
    const int pos = cnt + (int)__popcll(mask & ((1ull << lane) - 1ull));
    if (in && pos < KNBR) {
      sh_idx[wave][pos] = p;
      sh_gx[wave][pos * 3 + 0] = dx;
      sh_gx[wave][pos * 3 + 1] = dy;
      sh_gx[wave][pos * 3 + 2] = dz;
    }
    cnt += (int)__popcll(mask);
  }
  if (cnt == 0 && lane == 0) {
    sh_idx[wave][0] = 0;
    sh_gx[wave][0] = px[0] - cx;
    sh_gx[wave][1] = px[1] - cy;
    sh_gx[wave][2] = px[2] - cz;
  }
  const int nf0 = (cnt < 1) ? 1 : cnt;
  const int nf = (nf0 < KNBR) ? nf0 : KNBR;
  __syncthreads();
  if (lane < KNBR && lane >= nf) {
    sh_idx[wave][lane] = sh_idx[wave][0];
    sh_gx[wave][lane * 3 + 0] = sh_gx[wave][0];
    sh_gx[wave][lane * 3 + 1] = sh_gx[wave][1];
    sh_gx[wave][lane * 3 + 2] = sh_gx[wave][2];
  }
  __syncthreads();

  float* ox = gxyz + (size_t)gw * KNBR * 3;
  const float* shf = sh_gx[wave];
  for (int j = lane; j < KNBR * 3; j += 64) ox[j] = shf[j];

  float* og = gfeat + (size_t)gw * KNBR * NCH;
  const float* pf = feat + (size_t)b * NPTS * NCH;
#pragma unroll 4
  for (int k = 0; k < KNBR; ++k) {
    const int row = sh_idx[wave][k];
    const float2 v = ((const float2*)(pf + (size_t)row * NCH))[lane];
    ((float2*)(og + (size_t)k * NCH))[lane] = v;
  }
}

extern "C" void kernel_launch(void* const* d_in, const int* in_sizes, int n_in,
                              void* d_out, int out_size, void* d_ws, size_t ws_size,
                              hipStream_t stream) {
  const float* xyz = (const float*)d_in[0];
  const float* feat = (const float*)d_in[1];
  float* out = (float*)d_out;
  const int B = in_sizes[0] / (NPTS * 3);

  float* centroids = out;                                   // [B,S,3]
  float* gxyz = centroids + (size_t)B * NSAMP * 3;          // [B,S,K,3]
  float* gfeat = gxyz + (size_t)B * NSAMP * KNBR * 3;       // [B,S,K,C]

  const size_t slots_bytes =
      (size_t)B * 2 * FPB2 * sizeof(unsigned long long);
  if (d_ws != nullptr && ws_size >= slots_bytes) {
    unsigned long long* slots = (unsigned long long*)d_ws;
    init_slots<<<1, 256, 0, stream>>>(slots, B * 2 * FPB2);
    fps_mb2_kernel<<<B * FPB2, W2_TPB, 0, stream>>>(xyz, centroids, slots);
  } else {
    fps_kernel<<<B, FPS_TPB, 0, stream>>>(xyz, centroids);  // fallback
  }
  group_kernel<<<(B * NSAMP) / 4, 256, 0, stream>>>(xyz, feat, centroids, gxyz,
                                                    gfeat);
}

// Round 3
// 1830.500 us; speedup vs baseline: 1.1516x; 1.0429x over previous
//
#include <hip/hip_runtime.h>
#include <cstdint>
#include <cstddef>

// Problem constants (match reference setup_inputs)
#define NPTS 16384   // N
#define NSAMP 1024   // SAMPLES
#define KNBR 32      // MAX_NEIGHBORS
#define NCH 128      // C

// ---------------------------------------------------------------------------
// ROUND-6 THEORY: rounds 4-5 proved cross-block FPS is latency-bound on the
// LLC handshake (~3400 cyc/iter floor; stripping ALL local work moved 1997us
// only to 1816us). Round-0 single-block is the same speed (1808us) but is
// VALU-ISSUE-bound (active-CU VALUBusy 76% => ~3200 cyc/iter of issue) --
// attackable by cutting instructions. Round 6: packed f32 math. 32 pts/thread
// as 16 f32x2 pairs: per pair 8 v_pk ops (3 sub, 3 mul, 2 add) + 2 v_min
// + 6 argmax = 16 insts vs 24 scalar (x0.67). Downside bounded: if clang
// scalarizes, count == round-0 => no regression.
//
// Exactness contract (absmax 0): per-element IEEE identical to round-0:
// d = (dx*dx+dy*dy)+dz*dz with contract(off) (v_pk_add/mul are elementwise
// IEEE; no pk_fma contraction), md = fminf(md, d). Argmax tie-break =
// smallest global index: point p = slot*512 + t, pair j = slots (2j, 2j+1);
// in-pair strict > picks .x (smaller slot) on ties; running strict > keeps
// the earlier pair (smaller slot); cross-lane/wave via u64 key
// (f32bits(val)<<32)|~bi -- min-dists >= 0 so f32 bits are u32-monotone,
// ~bi makes larger key == smaller index on value ties.
//
// ROUND-3 LESSON retained: amdgpu_waves_per_eu(2,2) pins the occupancy
// target so the allocator gets a 256-VGPR budget and keeps all 128 coord/md
// registers resident (no rematerialization). Only 4 blocks exist -> free.
// ---------------------------------------------------------------------------

#define FPS_TPB 512

typedef float f32x2 __attribute__((ext_vector_type(2)));

#define PR16_FOREACH(X) \
  X(0) X(1) X(2) X(3) X(4) X(5) X(6) X(7) \
  X(8) X(9) X(10) X(11) X(12) X(13) X(14) X(15)

__global__ __launch_bounds__(FPS_TPB)
__attribute__((amdgpu_waves_per_eu(2, 2)))
void fps_kernel(
    const float* __restrict__ xyz, float* __restrict__ centroids) {
#pragma clang fp contract(off)
  const int b = blockIdx.x;
  const int t = threadIdx.x;
  const float* __restrict__ px = xyz + (size_t)b * NPTS * 3;

#define DECL_PR(j) f32x2 X##j, Y##j, Z##j, M##j;
  PR16_FOREACH(DECL_PR)
#undef DECL_PR

#define LOAD_PR(j)                                  \
  {                                                 \
    const int pa = (2 * (j)) * FPS_TPB + t;         \
    const int pb = pa + FPS_TPB;                    \
    X##j.x = px[pa * 3 + 0];                        \
    Y##j.x = px[pa * 3 + 1];                        \
    Z##j.x = px[pa * 3 + 2];                        \
    X##j.y = px[pb * 3 + 0];                        \
    Y##j.y = px[pb * 3 + 1];                        \
    Z##j.y = px[pb * 3 + 2];                        \
    M##j = {1e10f, 1e10f};                          \
  }
  PR16_FOREACH(LOAD_PR)
#undef LOAD_PR

  __shared__ unsigned long long s_wkey[2][FPS_TPB / 64];  // parity dbuf

  float* co = centroids + (size_t)b * NSAMP * 3;
  float lx = px[0], ly = px[1], lz = px[2];
  if (t == 0) { co[0] = lx; co[1] = ly; co[2] = lz; }

  for (int s = 1; s < NSAMP; ++s) {
    const int par = s & 1;
    const f32x2 cx = {lx, lx};
    const f32x2 cy = {ly, ly};
    const f32x2 cz = {lz, lz};

    float bv = -1.0f;
    int bs = 0;  // best slot 0..31 (compile-time consts feed cndmask)
#define UPD_PR(j)                                                       \
    {                                                                   \
      f32x2 dx = X##j - cx, dy = Y##j - cy, dz = Z##j - cz;             \
      f32x2 dd = (dx * dx + dy * dy) + dz * dz; /* no FMA */            \
      M##j.x = fminf(M##j.x, dd.x);                                     \
      M##j.y = fminf(M##j.y, dd.y);                                     \
      float vj; int sj;                                                 \
      if (M##j.y > M##j.x) { vj = M##j.y; sj = 2 * (j) + 1; }           \
      else                 { vj = M##j.x; sj = 2 * (j); }               \
      if (vj > bv) { bv = vj; bs = sj; }  /* strict >: min index */     \
    }
    PR16_FOREACH(UPD_PR)
#undef UPD_PR

    const unsigned int bi = ((unsigned int)bs << 9) | (unsigned int)t;
    unsigned long long key =
        ((unsigned long long)__float_as_uint(bv) << 32) |
        (unsigned int)(~bi);

    // intra-wave butterfly max (6 steps over 64 lanes)
#pragma unroll
    for (int off = 1; off < 64; off <<= 1) {
      const unsigned long long ok = __shfl_xor(key, off);
      if (ok > key) key = ok;
    }
    if ((t & 63) == 0) s_wkey[par][t >> 6] = key;
    __syncthreads();  // the ONLY barrier per iteration (LDS double-buffered)

    // replicated cross-wave reduce: all threads read the 8 wave winners
    // (same-address LDS reads broadcast, no conflicts)
    unsigned long long best = s_wkey[par][0];
#pragma unroll
    for (int w = 1; w < FPS_TPB / 64; ++w) {
      const unsigned long long k2 = s_wkey[par][w];
      if (k2 > best) best = k2;
    }
    // uniform by construction; readfirstlane makes it provable -> scalar load
    const unsigned int widx =
        (unsigned int)__builtin_amdgcn_readfirstlane((int)(~(unsigned int)best));

    lx = px[widx * 3 + 0];
    ly = px[widx * 3 + 1];
    lz = px[widx * 3 + 2];
    if (t == 0) {
      co[s * 3 + 0] = lx;
      co[s * 3 + 1] = ly;
      co[s * 3 + 2] = lz;
    }
  }
}

// ---------------------------------------------------------------------------
// Kernel 2: ball query (first K in-radius by index order, pad with first hit)
// + gather. One wave per (b,s) centroid; 4 waves per 256-thread block.
// Validated bit-exact in round 0; unchanged.
// ---------------------------------------------------------------------------
__global__ __launch_bounds__(256) void group_kernel(
    const float* __restrict__ xyz, const float* __restrict__ feat,
    const float* __restrict__ centroids,
    float* __restrict__ gxyz, float* __restrict__ gfeat) {
#pragma clang fp contract(off)
  const int wave = threadIdx.x >> 6;
  const int lane = threadIdx.x & 63;
  const int gw = blockIdx.x * 4 + wave;  // == b * NSAMP + s
  const int b = gw >> 10;

  const float* px = xyz + (size_t)b * NPTS * 3;
  const float* pc = centroids + (size_t)gw * 3;
  const float cx = pc[0], cy = pc[1], cz = pc[2];
  // float32(0.04): numpy compares f32 sqd against python-double 0.04 demoted
  // to f32. NOT 0.2f*0.2f (that's a different float, 1 ulp larger).
  const float rr = 0.04f;

  __shared__ int sh_idx[4][KNBR];
  __shared__ float sh_gx[4][KNBR * 3];

  int cnt = 0;
  for (int n0 = 0; n0 < NPTS && cnt < KNBR; n0 += 64) {
    const int p = n0 + lane;
    const float xx = px[p * 3 + 0];
    const float yy = px[p * 3 + 1];
    const float zz = px[p * 3 + 2];
    const float dx = xx - cx;
    const float dy = yy - cy;
    const float dz = zz - cz;
    const float d = (dx * dx + dy * dy) + dz * dz;  // contract(off): no FMA
    const bool in = d <= rr;
    const unsigned long long mask = __ballot(in);
    const int pos = cnt + (int)__popcll(mask & ((1ull << lane) - 1ull));
    if (in && pos < KNBR) {
      sh_idx[wave][pos] = p;
      sh_gx[wave][pos * 3 + 0] = dx;
      sh_gx[wave][pos * 3 + 1] = dy;
      sh_gx[wave][pos * 3 + 2] = dz;
    }
    cnt += (int)__popcll(mask);
  }
  // Safety: cannot happen (centroid is itself in-ball), but avoid garbage
  // indices if it somehow does.
  if (cnt == 0 && lane == 0) {
    sh_idx[wave][0] = 0;
    sh_gx[wave][0] = px[0] - cx;
    sh_gx[wave][1] = px[1] - cy;
    sh_gx[wave][2] = px[2] - cz;
  }
  const int nf0 = (cnt < 1) ? 1 : cnt;
  const int nf = (nf0 < KNBR) ? nf0 : KNBR;
  __syncthreads();
  // pad slots [nf, K) with the first hit (matches reference padding)
  if (lane < KNBR && lane >= nf) {
    sh_idx[wave][lane] = sh_idx[wave][0];
    sh_gx[wave][lane * 3 + 0] = sh_gx[wave][0];
    sh_gx[wave][lane * 3 + 1] = sh_gx[wave][1];
    sh_gx[wave][lane * 3 + 2] = sh_gx[wave][2];
  }
  __syncthreads();

  // write grouped_xyz: 96 floats per centroid
  float* ox = gxyz + (size_t)gw * KNBR * 3;
  const float* shf = sh_gx[wave];
  for (int j = lane; j < KNBR * 3; j += 64) ox[j] = shf[j];

  // gather features: K rows of 128 floats, float2 per lane (512 B/row)
  float* og = gfeat + (size_t)gw * KNBR * NCH;
  const float* pf = feat + (size_t)b * NPTS * NCH;
#pragma unroll 4
  for (int k = 0; k < KNBR; ++k) {
    const int row = sh_idx[wave][k];
    const float2 v = ((const float2*)(pf + (size_t)row * NCH))[lane];
    ((float2*)(og + (size_t)k * NCH))[lane] = v;
  }
}

extern "C" void kernel_launch(void* const* d_in, const int* in_sizes, int n_in,
                              void* d_out, int out_size, void* d_ws, size_t ws_size,
                              hipStream_t stream) {
  const float* xyz = (const float*)d_in[0];
  const float* feat = (const float*)d_in[1];
  float* out = (float*)d_out;
  const int B = in_sizes[0] / (NPTS * 3);

  float* centroids = out;                                   // [B,S,3]
  float* gxyz = centroids + (size_t)B * NSAMP * 3;          // [B,S,K,3]
  float* gfeat = gxyz + (size_t)B * NSAMP * KNBR * 3;       // [B,S,K,C]

  fps_kernel<<<B, FPS_TPB, 0, stream>>>(xyz, centroids);
  group_kernel<<<(B * NSAMP) / 4, 256, 0, stream>>>(xyz, feat, centroids, gxyz,
                                                    gfeat);
}